// Round 1
// baseline (73.098 us; speedup 1.0000x reference)
//
#include <hip/hip_runtime.h>

constexpr int   NN     = 8192;
constexpr float MARGIN = 0.01f;
constexpr int   TILE   = 256;        // threads per block == j-chunk size
constexpr int   NT     = NN / TILE;  // 32 tiles per dimension

// Each block: i-tile (one i per thread) x j-tile (staged in LDS).
// Symmetry: hinge(i,j) == hinge(j,i) and validity is symmetric, so we
// process only jb >= ib tiles and double the off-diagonal contributions.
// Diagonal pairs (i==j) have act_diff == 0 -> excluded automatically.
__global__ __launch_bounds__(TILE)
void pair_kernel(const float* __restrict__ pred,
                 const float* __restrict__ act,
                 const float* __restrict__ prev,
                 double* __restrict__ price_sum,
                 double* __restrict__ rank_sum,
                 unsigned long long* __restrict__ count)
{
    const int ib = blockIdx.x;
    const int jb = blockIdx.y;
    if (jb < ib) return;

    __shared__ float s_pr[TILE];
    __shared__ float s_ar[TILE];

    const int tid = threadIdx.x;
    const int i   = ib * TILE + tid;

    // stage j-chunk returns into LDS
    {
        const int j  = jb * TILE + tid;
        const float pv = prev[j];
        s_pr[tid] = (pred[j] - pv) / pv;
        s_ar[tid] = (act[j]  - pv) / pv;
    }

    const float pv  = prev[i];
    const float pri = (pred[i] - pv) / pv;
    const float ari = (act[i]  - pv) / pv;

    // fuse the MSE price term into diagonal blocks (each i counted once)
    double psum = 0.0;
    if (ib == jb) {
        const float d = pred[i] - act[i];
        psum = (double)(d * d);
    }

    __syncthreads();

    double sum = 0.0;
    int    cnt = 0;
#pragma unroll 16
    for (int j = 0; j < TILE; ++j) {
        const float ad = ari - s_ar[j];        // act_diff
        const float pd = pri - s_pr[j];        // pred_diff
        const float s  = (ad > 0.0f) ? 1.0f : -1.0f;
        const float h  = fmaxf(0.0f, MARGIN - s * pd);
        if (ad != 0.0f) {                      // valid (symmetric)
            sum += (double)h;
            cnt += 1;
        }
    }

    if (ib != jb) { sum *= 2.0; cnt *= 2; }

    // wave-64 butterfly reduction
    for (int off = 32; off > 0; off >>= 1) {
        sum  += __shfl_down(sum,  off, 64);
        cnt  += __shfl_down(cnt,  off, 64);
        psum += __shfl_down(psum, off, 64);
    }
    if ((tid & 63) == 0) {
        atomicAdd(rank_sum, sum);
        atomicAdd(count, (unsigned long long)cnt);
        if (ib == jb) atomicAdd(price_sum, psum);
    }
}

__global__ void finalize_kernel(const double* __restrict__ price_sum,
                                const double* __restrict__ rank_sum,
                                const unsigned long long* __restrict__ count,
                                float* __restrict__ out)
{
    const double price_loss = price_sum[0] / (double)NN;
    const double ranking    = (count[0] > 0ULL)
                                ? rank_sum[0] / (double)count[0]
                                : 0.0;
    out[0] = (float)(0.5 * price_loss + 0.5 * ranking);
}

extern "C" void kernel_launch(void* const* d_in, const int* in_sizes, int n_in,
                              void* d_out, int out_size, void* d_ws, size_t ws_size,
                              hipStream_t stream)
{
    const float* pred = (const float*)d_in[0];
    const float* act  = (const float*)d_in[1];
    const float* prev = (const float*)d_in[2];

    double* price_sum = (double*)d_ws;
    double* rank_sum  = price_sum + 1;
    unsigned long long* count = (unsigned long long*)(price_sum + 2);

    hipMemsetAsync(d_ws, 0, 3 * sizeof(double), stream);

    dim3 grid(NT, NT);
    pair_kernel<<<grid, TILE, 0, stream>>>(pred, act, prev,
                                           price_sum, rank_sum, count);
    finalize_kernel<<<1, 1, 0, stream>>>(price_sum, rank_sum, count,
                                         (float*)d_out);
}

// Round 2
// 19.048 us; speedup vs baseline: 3.8377x; 3.8377x over previous
//
#include <hip/hip_runtime.h>

constexpr int    NN     = 8192;
constexpr float  MARGIN = 0.01f;
constexpr int    TI     = 256;           // i-rows per block == threads
constexpr int    TJ     = 128;           // j-chunk per block
constexpr int    NTI    = NN / TI;       // 32
constexpr int    NTJ    = NN / TJ;       // 64
// blocks: for each ib, jc in [2*ib, NTJ)  ->  sum = 1056
constexpr int    NBLOCKS = NTJ * NTI - NTI * (NTI - 1); // 2048 - 992 = 1056

// Symmetry: hinge(i,j)==hinge(j,i), validity symmetric, diagonal invalid.
// j-chunks with jc >= 2*ib+2 are strictly off the 256x256 diagonal tile ->
// their (i,j) pairs are counted once here, doubled. jc in {2ib, 2ib+1} lie
// inside the diagonal tile -> all ordered pairs processed once, no doubling.
__global__ __launch_bounds__(TI)
void pair_kernel(const float* __restrict__ pred,
                 const float* __restrict__ act,
                 const float* __restrict__ prev,
                 double* __restrict__ partials)   // [NBLOCKS][3]: rank, price, cnt
{
    // decode flat block id -> (ib, jc), row ib has (NTJ - 2*ib) tiles
    int t  = blockIdx.x;
    int ib = 0;
    while (t >= NTJ - 2 * ib) { t -= NTJ - 2 * ib; ++ib; }
    const int  jc        = 2 * ib + t;
    const bool diag_like = (t < 2);        // jc == 2ib or 2ib+1
    const bool do_price  = (t == 0);       // one chunk per i-row-tile owns MSE

    __shared__ float2 s_t[TJ];             // {pred_r, act_r} per j

    const int tid = threadIdx.x;
    if (tid < TJ) {
        const int   j  = jc * TJ + tid;
        const float pv = prev[j];
        s_t[tid] = make_float2((pred[j] - pv) / pv, (act[j] - pv) / pv);
    }

    const int   i   = ib * TI + tid;
    const float pv  = prev[i];
    const float pri = (pred[i] - pv) / pv;
    const float ari = (act[i]  - pv) / pv;

    double pp = 0.0;
    if (do_price) {
        const float d = pred[i] - act[i];
        pp = (double)(d * d);
    }

    __syncthreads();

    float a0 = 0.f, a1 = 0.f, a2 = 0.f, a3 = 0.f;
    int   c0 = 0, c1 = 0;

#define PAIR(tv, acc, cc)                                  \
    {                                                      \
        const float ad = ari - (tv).y;                     \
        const float pd = pri - (tv).x;                     \
        const float u  = (ad > 0.0f) ? -pd : pd;           \
        const float h  = fmaxf(0.0f, MARGIN + u);          \
        const bool  v  = (ad != 0.0f);                     \
        acc += v ? h : 0.0f;                               \
        cc  += v ? 1 : 0;                                  \
    }

#pragma unroll 8
    for (int j = 0; j < TJ; j += 4) {
        const float2 t0 = s_t[j + 0];
        const float2 t1 = s_t[j + 1];
        const float2 t2 = s_t[j + 2];
        const float2 t3 = s_t[j + 3];
        PAIR(t0, a0, c0);
        PAIR(t1, a1, c1);
        PAIR(t2, a2, c0);
        PAIR(t3, a3, c1);
    }
#undef PAIR

    double wsum = (double)((a0 + a1) + (a2 + a3));
    int    cnt  = c0 + c1;
    if (!diag_like) { wsum *= 2.0; cnt <<= 1; }

    // wave-64 butterfly
    for (int off = 32; off > 0; off >>= 1) {
        wsum += __shfl_down(wsum, off, 64);
        cnt  += __shfl_down(cnt,  off, 64);
        pp   += __shfl_down(pp,   off, 64);
    }

    __shared__ double rs[4], rp[4];
    __shared__ int    rc[4];
    const int w = tid >> 6;
    if ((tid & 63) == 0) { rs[w] = wsum; rp[w] = pp; rc[w] = cnt; }
    __syncthreads();
    if (tid == 0) {
        partials[3 * blockIdx.x + 0] = rs[0] + rs[1] + rs[2] + rs[3];
        partials[3 * blockIdx.x + 1] = rp[0] + rp[1] + rp[2] + rp[3];
        partials[3 * blockIdx.x + 2] = (double)(rc[0] + rc[1] + rc[2] + rc[3]);
    }
}

__global__ __launch_bounds__(256)
void finalize_kernel(const double* __restrict__ partials,
                     float* __restrict__ out)
{
    double s = 0.0, p = 0.0, c = 0.0;
    for (int t = threadIdx.x; t < NBLOCKS; t += 256) {
        s += partials[3 * t + 0];
        p += partials[3 * t + 1];
        c += partials[3 * t + 2];
    }
    for (int off = 32; off > 0; off >>= 1) {
        s += __shfl_down(s, off, 64);
        p += __shfl_down(p, off, 64);
        c += __shfl_down(c, off, 64);
    }
    __shared__ double rs[4], rp[4], rc[4];
    const int w = threadIdx.x >> 6;
    if ((threadIdx.x & 63) == 0) { rs[w] = s; rp[w] = p; rc[w] = c; }
    __syncthreads();
    if (threadIdx.x == 0) {
        const double S = rs[0] + rs[1] + rs[2] + rs[3];
        const double P = rp[0] + rp[1] + rp[2] + rp[3];
        const double C = rc[0] + rc[1] + rc[2] + rc[3];
        const double price_loss = P / (double)NN;
        const double rank       = (C > 0.0) ? S / C : 0.0;
        out[0] = (float)(0.5 * price_loss + 0.5 * rank);
    }
}

extern "C" void kernel_launch(void* const* d_in, const int* in_sizes, int n_in,
                              void* d_out, int out_size, void* d_ws, size_t ws_size,
                              hipStream_t stream)
{
    const float* pred = (const float*)d_in[0];
    const float* act  = (const float*)d_in[1];
    const float* prev = (const float*)d_in[2];

    double* partials = (double*)d_ws;   // NBLOCKS * 3 * 8 = 25344 bytes

    pair_kernel<<<NBLOCKS, TI, 0, stream>>>(pred, act, prev, partials);
    finalize_kernel<<<1, 256, 0, stream>>>(partials, (float*)d_out);
}